// Round 22
// baseline (637.178 us; speedup 1.0000x reference)
//
#include <hip/hip_runtime.h>
#include <hip/hip_bf16.h>

// SACRSN_v84 — v22: row blocks process 4 consecutive rows sequentially with
// next-row mem/z prefetch (HBM latency hides under current row's compute;
// weights L1/L2-warm for rows 2-4). Phase bodies byte-identical to R19 (best).
// vq path unchanged. Grid: 1024 vq blocks + 2048 row blocks.

#define NROWS 8
#define RSTRIDE 4736

static constexpr size_t OFF_VQLOSS = 38797312UL;
static constexpr size_t OFF_IDX    = 38805504UL;
static constexpr size_t OFF_SENT   = 38813696UL;
static constexpr size_t OFF_NENT   = 38813697UL;

struct Params {
  const float* curr_r; const float* curr_i;
  const float* mem_r;  const float* mem_i;
  const float* codebook;
  const float* qkv_Wr; const float* qkv_Wi; const float* qkv_br; const float* qkv_bi;
  const float* quad_Wr; const float* quad_Wi; const float* quad_br; const float* quad_bi;
  const float* sens_Wr; const float* sens_Wi; const float* sens_br; const float* sens_bi;
  const float* vis_pal; const float* aud_pal;
  const float* gate_W; const float* gate_b;
  const float* addr_W; const float* addr_b;
  const float* ln_gr; const float* ln_br; const float* ln_gi; const float* ln_bi;
  float* out;
  int* hist;
  float* rowent;
};

__device__ __forceinline__ float ftanh(float x) {
  const float e = __expf(2.0f * x);
  return 1.0f - 2.0f / (e + 1.0f);
}
__device__ __forceinline__ float fsigm(float x) {
  return 1.0f / (1.0f + __expf(-x));
}

union __align__(16) SharedU {
  struct {          // row path (~11.8 KB)
    float zr[64], zi[64];
    float s_qr[64], s_qi[64], s_kr[64], s_ki[64], s_vr[64], s_vi[64];
    float sfl[128];
    float s_sp[4][4][64];
    float lp[4][32];
    float s_eff[32];
    float s_sim[32], s_attn[32];
    float s_rr[4][8][8], s_ri[4][8][8];
    float s_pv[4][32], s_pa[4][32];
    float s_pvp[32], s_pap[32];
    float s_vo[128], s_ao[128];
    float s_wg, s_gate;
  } r;
  struct {          // vq path (~13.3 KB)
    float s_zr[NROWS][64], s_zi[NROWS][64];
    double s_cbn[128];
    double s_dall4[4][256];
    float s_vqls[NROWS];
    int s_idx[NROWS];
  } v;
};

__global__ __launch_bounds__(256) void main_kernel(Params P) {
  __shared__ SharedU u;
  const int t = threadIdx.x;
  const int lane = t & 63;
  const int wv = t >> 6;

  if (blockIdx.x < 1024) {
    // ================= VQ path (verbatim R19) =================
    const int bid = blockIdx.x;
    {
      const float* cr = P.curr_r + (size_t)bid * (NROWS * 64);
      const float* ci = P.curr_i + (size_t)bid * (NROWS * 64);
      float* zr = &u.v.s_zr[0][0];
      float* zi = &u.v.s_zi[0][0];
      for (int i = t; i < NROWS * 64; i += 256) { zr[i] = cr[i]; zi[i] = ci[i]; }
    }
    {
      const float* cb = P.codebook + (t & 127) * 128 + (t >> 7) * 64;
      double a = 0.0;
      for (int d = 0; d < 64; ++d) { double w = (double)cb[d]; a = fma(w, w, a); }
      __syncthreads();
      ((double*)&u.v.s_dall4[0][0])[t] = a;
      __syncthreads();
      if (t < 128) u.v.s_cbn[t] = ((double*)&u.v.s_dall4[0][0])[t]
                                 + ((double*)&u.v.s_dall4[0][0])[t + 128];
      __syncthreads();
    }
    {
      const int c = t & 127, h = t >> 7;
      const float* cb = P.codebook + c * 128 + h * 64;
      const float (*zb)[64] = h ? u.v.s_zi : u.v.s_zr;
      #pragma unroll 1
      for (int p = 0; p < 2; ++p) {
        double acc[4];
        #pragma unroll
        for (int rr = 0; rr < 4; ++rr) acc[rr] = 0.0;
        for (int d = 0; d < 64; ++d) {
          const double w = (double)cb[d];
          #pragma unroll
          for (int rr = 0; rr < 4; ++rr) acc[rr] = fma(w, (double)zb[p * 4 + rr][d], acc[rr]);
        }
        #pragma unroll
        for (int rr = 0; rr < 4; ++rr) u.v.s_dall4[rr][h * 128 + c] = acc[rr];
        __syncthreads();
        {
          const int r = p * 4 + wv;
          const double d0 = u.v.s_cbn[lane]      - 2.0 * (u.v.s_dall4[wv][lane]      + u.v.s_dall4[wv][128 + lane]);
          const double d1 = u.v.s_cbn[lane + 64] - 2.0 * (u.v.s_dall4[wv][64 + lane] + u.v.s_dall4[wv][192 + lane]);
          double sv = d0; int si = lane;
          if (d1 < sv) { sv = d1; si = lane + 64; }
          #pragma unroll
          for (int m = 1; m <= 32; m <<= 1) {
            double ov = __shfl_xor(sv, m);
            int oi = __shfl_xor(si, m);
            if (ov < sv || (ov == sv && oi < si)) { sv = ov; si = oi; }
          }
          if (lane == 0) { u.v.s_idx[r] = si; atomicAdd(&P.hist[si], 1); }
        }
        __syncthreads();
      }
    }
    {
      #pragma unroll
      for (int rr = 0; rr < 2; ++rr) {
        const int r = wv * 2 + rr;
        const float* cb = P.codebook + (size_t)u.v.s_idx[r] * 128;
        float d0_ = cb[lane] - u.v.s_zr[r][lane];
        float d1_ = cb[64 + lane] - u.v.s_zi[r][lane];
        float v = d0_ * d0_ + d1_ * d1_;
        #pragma unroll
        for (int m = 1; m <= 32; m <<= 1) v += __shfl_xor(v, m);
        if (lane == 0) u.v.s_vqls[r] = 0.25f * v * (1.0f / 128.0f);
      }
    }
    __syncthreads();
    {
      const int j = t & 63, g = t >> 6;
      #pragma unroll
      for (int rr = 0; rr < 4; ++rr) {
        const int r = (g >> 1) * 4 + rr;
        float* orow = P.out + ((size_t)bid * NROWS + r) * RSTRIDE;
        const float* cb = P.codebook + (size_t)u.v.s_idx[r] * 128;
        if ((g & 1) == 0) {
          float z = u.v.s_zr[r][j];
          orow[j] = z + (cb[j] - z);
        } else {
          float z = u.v.s_zi[r][j];
          orow[64 + j] = z + (cb[64 + j] - z);
        }
      }
    }
    if (t < NROWS) {
      P.out[OFF_VQLOSS + (size_t)bid * NROWS + t] = u.v.s_vqls[t];
      P.out[OFF_IDX + (size_t)bid * NROWS + t] = (float)u.v.s_idx[t];
    }
    return;
  }

  // ================= Row path: 4 rows sequential with prefetch =================
  const int base = (blockIdx.x - 1024) * 4;
  const int s = t >> 3, k = t & 7, d0 = k * 8;

  float mrC[8], miC[8], mrN[8], miN[8];
  {
    const size_t bb0 = (size_t)base;
    const float* mrp = P.mem_r + ((bb0 * 32 + s) * 64 + d0);
    const float* mip = P.mem_i + ((bb0 * 32 + s) * 64 + d0);
    float4 a0 = *(const float4*)mrp, a1 = *(const float4*)(mrp + 4);
    float4 b0 = *(const float4*)mip, b1 = *(const float4*)(mip + 4);
    mrC[0]=a0.x; mrC[1]=a0.y; mrC[2]=a0.z; mrC[3]=a0.w; mrC[4]=a1.x; mrC[5]=a1.y; mrC[6]=a1.z; mrC[7]=a1.w;
    miC[0]=b0.x; miC[1]=b0.y; miC[2]=b0.z; miC[3]=b0.w; miC[4]=b1.x; miC[5]=b1.y; miC[6]=b1.z; miC[7]=b1.w;
    if (t < 64)       u.r.zr[t]      = P.curr_r[bb0 * 64 + t];
    else if (t < 128) u.r.zi[t - 64] = P.curr_i[bb0 * 64 + (t - 64)];
  }
  __syncthreads();

  #pragma unroll
  for (int rr = 0; rr < 4; ++rr) {
    const int b = base + rr;
    const size_t bb = (size_t)b;
    float* orow = P.out + bb * RSTRIDE;

    // prefetch next row's mem + z (latency hides under phases B..E)
    float zn = 0.f;
    if (rr < 3) {
      const size_t bn = bb + 1;
      const float* mrp = P.mem_r + ((bn * 32 + s) * 64 + d0);
      const float* mip = P.mem_i + ((bn * 32 + s) * 64 + d0);
      float4 a0 = *(const float4*)mrp, a1 = *(const float4*)(mrp + 4);
      float4 b0 = *(const float4*)mip, b1 = *(const float4*)(mip + 4);
      mrN[0]=a0.x; mrN[1]=a0.y; mrN[2]=a0.z; mrN[3]=a0.w; mrN[4]=a1.x; mrN[5]=a1.y; mrN[6]=a1.z; mrN[7]=a1.w;
      miN[0]=b0.x; miN[1]=b0.y; miN[2]=b0.z; miN[3]=b0.w; miN[4]=b1.x; miN[5]=b1.y; miN[6]=b1.z; miN[7]=b1.w;
      if (t < 64)       zn = P.curr_r[bn * 64 + t];
      else if (t < 128) zn = P.curr_i[bn * 64 + (t - 64)];
    }

    // ---- B: clinears q,k,v,quad (wave=cl) + sens partials ----
    {
      const int j = lane, cl = wv;
      const float *Wr, *Wi, *br_, *bi_;
      if      (cl == 0) { Wr = P.qkv_Wr;        Wi = P.qkv_Wi;        br_ = P.qkv_br;       bi_ = P.qkv_bi;       }
      else if (cl == 1) { Wr = P.qkv_Wr + 4096; Wi = P.qkv_Wi + 4096; br_ = P.qkv_br + 64;  bi_ = P.qkv_bi + 64;  }
      else if (cl == 2) { Wr = P.qkv_Wr + 8192; Wi = P.qkv_Wi + 8192; br_ = P.qkv_br + 128; bi_ = P.qkv_bi + 128; }
      else              { Wr = P.quad_Wr;       Wi = P.quad_Wi;       br_ = P.quad_br;      bi_ = P.quad_bi;      }
      float aRR = 0.f, aRI = 0.f, aIR = 0.f, aII = 0.f;
      for (int d = 0; d < 64; ++d) {
        const float xr = u.r.zr[d], xi = u.r.zi[d];
        const float wr = Wr[d * 64 + j], wi = Wi[d * 64 + j];
        aRR += xr * wr; aRI += xr * wi; aIR += xi * wr; aII += xi * wi;
      }
      const float oR = (aRR + br_[j]) - (aII + bi_[j]);
      const float oI = (aRI + bi_[j]) + (aIR + br_[j]);
      if      (cl == 0) { u.r.s_qr[j] = oR; u.r.s_qi[j] = oI; }
      else if (cl == 1) { u.r.s_kr[j] = oR; u.r.s_ki[j] = oI; }
      else if (cl == 2) { u.r.s_vr[j] = oR; u.r.s_vi[j] = oI; }
      else              { orow[512 + j] = -oI; orow[576 + j] = oR; }
      float bRR = 0.f, bRI = 0.f, bIR = 0.f, bII = 0.f;
      for (int dd = 0; dd < 16; ++dd) {
        const int d = wv * 16 + dd;
        const float xr = u.r.zr[d], xi = u.r.zi[d];
        const float wr = P.sens_Wr[d * 64 + j], wi = P.sens_Wi[d * 64 + j];
        bRR += xr * wr; bRI += xr * wi; bIR += xi * wr; bII += xi * wi;
      }
      u.r.s_sp[wv][0][j] = bRR; u.r.s_sp[wv][1][j] = bRI;
      u.r.s_sp[wv][2][j] = bIR; u.r.s_sp[wv][3][j] = bII;
    }
    __syncthreads();

    // ---- C: sim partials + addr partials + wgate + gate ----
    {
      float sp = 0.f;
      #pragma unroll
      for (int x = 0; x < 8; ++x) sp += mrC[x] * u.r.zr[d0 + x] + miC[x] * u.r.zi[d0 + x];
      sp += __shfl_xor(sp, 1); sp += __shfl_xor(sp, 2); sp += __shfl_xor(sp, 4);
      if (k == 0) u.r.s_sim[s] = sp;
    }
    if (t < 128) {
      const int q = t >> 5, l = t & 31;
      const float* zz = (q < 2) ? u.r.zr : u.r.zi;
      const int zb = (q & 1) * 32;
      float a = 0.f;
      for (int i = 0; i < 32; ++i) a += zz[zb + i] * P.addr_W[(q * 32 + i) * 32 + l];
      u.r.lp[q][l] = a;
    } else if (t < 192) {
      const int j = t - 128;
      float tw = u.r.zr[j] * P.gate_W[j] + u.r.zi[j] * P.gate_W[64 + j];
      #pragma unroll
      for (int m = 1; m <= 32; m <<= 1) tw += __shfl_xor(tw, m);
      if (j == 0) u.r.s_wg = tw;
    } else {
      const int j = t - 192;
      float g = u.r.s_qr[j] * u.r.s_kr[j] + u.r.s_qi[j] * u.r.s_ki[j];
      #pragma unroll
      for (int m = 1; m <= 32; m <<= 1) g += __shfl_xor(g, m);
      if (j == 0) u.r.s_gate = fsigm(g);
    }
    __syncthreads();

    // ---- D: sim softmax | addr softmax/top3/eff | sens combine ----
    if (t < 32) {
      float v = u.r.s_sim[t];
      float mx = v;
      #pragma unroll
      for (int m = 16; m >= 1; m >>= 1) mx = fmaxf(mx, __shfl_xor(mx, m));
      float e = __expf(v - mx);
      float sm = e;
      #pragma unroll
      for (int m = 16; m >= 1; m >>= 1) sm += __shfl_xor(sm, m);
      u.r.s_attn[t] = e / sm;
    } else if (t >= 64 && t < 96) {
      const int l = t - 64;
      float lg = u.r.lp[0][l] + u.r.lp[1][l] + u.r.lp[2][l] + u.r.lp[3][l] + P.addr_b[l];
      float mx = lg;
      #pragma unroll
      for (int m = 16; m >= 1; m >>= 1) mx = fmaxf(mx, __shfl_xor(mx, m));
      float e = __expf(lg - mx);
      float sm = e;
      #pragma unroll
      for (int m = 16; m >= 1; m >>= 1) sm += __shfl_xor(sm, m);
      const float w = e / sm;
      float es = -(w * __logf(w + 1e-10f));
      #pragma unroll
      for (int m = 16; m >= 1; m >>= 1) es += __shfl_xor(es, m);
      if (l == 0) P.rowent[b] = es;
      const float myw = w;
      bool picked = false;
      float val = w; int idx = l;
      float sumtop = 0.f;
      #pragma unroll
      for (int it = 0; it < 3; ++it) {
        float v2 = val; int i2 = idx;
        #pragma unroll
        for (int m = 16; m >= 1; m >>= 1) {
          float ov = __shfl_xor(v2, m); int oi = __shfl_xor(i2, m);
          if (ov > v2 || (ov == v2 && oi < i2)) { v2 = ov; i2 = oi; }
        }
        sumtop += v2;
        if (l == i2) { picked = true; val = -1e30f; }
      }
      const float wgate = fsigm(u.r.s_wg + P.gate_b[0]);
      u.r.s_eff[l] = picked ? wgate * (myw / (sumtop + 1e-6f)) : 0.f;
    } else if (t >= 128 && t < 192) {
      const int j = t - 128;
      const float aRR = u.r.s_sp[0][0][j] + u.r.s_sp[1][0][j] + u.r.s_sp[2][0][j] + u.r.s_sp[3][0][j];
      const float aRI = u.r.s_sp[0][1][j] + u.r.s_sp[1][1][j] + u.r.s_sp[2][1][j] + u.r.s_sp[3][1][j];
      const float aIR = u.r.s_sp[0][2][j] + u.r.s_sp[1][2][j] + u.r.s_sp[2][2][j] + u.r.s_sp[3][2][j];
      const float aII = u.r.s_sp[0][3][j] + u.r.s_sp[1][3][j] + u.r.s_sp[2][3][j] + u.r.s_sp[3][3][j];
      const float oR = (aRR + P.sens_br[j]) - (aII + P.sens_bi[j]);
      const float oI = (aRI + P.sens_bi[j]) + (aIR + P.sens_br[j]);
      u.r.sfl[j] = oR; u.r.sfl[64 + j] = oI;
    }
    __syncthreads();

    // ---- E: read partials + tanh/LN + palette partials ----
    const float aw = u.r.s_attn[s];
    {
      float pr[8], pi[8];
      #pragma unroll
      for (int x = 0; x < 8; ++x) { pr[x] = aw * mrC[x]; pi[x] = aw * miC[x]; }
      #pragma unroll
      for (int m = 8; m <= 32; m <<= 1) {
        #pragma unroll
        for (int x = 0; x < 8; ++x) { pr[x] += __shfl_xor(pr[x], m); pi[x] += __shfl_xor(pi[x], m); }
      }
      if (lane < 8) {
        #pragma unroll
        for (int x = 0; x < 8; ++x) { u.r.s_rr[wv][lane][x] = pr[x]; u.r.s_ri[wv][lane][x] = pi[x]; }
      }
    }
    {
      const float eff = u.r.s_eff[s];
      float nr[8], ni[8];
      #pragma unroll
      for (int x = 0; x < 8; ++x) {
        nr[x] = ftanh(mrC[x] + eff * (u.r.zr[d0 + x] - mrC[x]));
        ni[x] = ftanh(miC[x] + eff * (u.r.zi[d0 + x] - miC[x]));
      }
      float sR = 0.f, sI = 0.f;
      #pragma unroll
      for (int x = 0; x < 8; ++x) { sR += nr[x]; sI += ni[x]; }
      sR += __shfl_xor(sR, 1); sR += __shfl_xor(sR, 2); sR += __shfl_xor(sR, 4);
      sI += __shfl_xor(sI, 1); sI += __shfl_xor(sI, 2); sI += __shfl_xor(sI, 4);
      const float mR = sR * (1.f / 64.f), mI = sI * (1.f / 64.f);
      float vR = 0.f, vI = 0.f;
      #pragma unroll
      for (int x = 0; x < 8; ++x) {
        const float dr = nr[x] - mR; vR += dr * dr;
        const float di = ni[x] - mI; vI += di * di;
      }
      vR += __shfl_xor(vR, 1); vR += __shfl_xor(vR, 2); vR += __shfl_xor(vR, 4);
      vI += __shfl_xor(vI, 1); vI += __shfl_xor(vI, 2); vI += __shfl_xor(vI, 4);
      const float invR = 1.f / sqrtf(vR * (1.f / 64.f) + 1e-6f);
      const float invI = 1.f / sqrtf(vI * (1.f / 64.f) + 1e-6f);
      float oR[8], oI[8];
      #pragma unroll
      for (int x = 0; x < 8; ++x) {
        const int d = d0 + x;
        oR[x] = (nr[x] - mR) * invR * P.ln_gr[d] + P.ln_br[d];
        oI[x] = (ni[x] - mI) * invI * P.ln_gi[d] + P.ln_bi[d];
      }
      *(float4*)&orow[640 + s * 64 + d0]      = make_float4(oR[0], oR[1], oR[2], oR[3]);
      *(float4*)&orow[640 + s * 64 + d0 + 4]  = make_float4(oR[4], oR[5], oR[6], oR[7]);
      *(float4*)&orow[2688 + s * 64 + d0]     = make_float4(oI[0], oI[1], oI[2], oI[3]);
      *(float4*)&orow[2688 + s * 64 + d0 + 4] = make_float4(oI[4], oI[5], oI[6], oI[7]);
    }
    if (t < 128) {
      const int a = t & 31, q = t >> 5;
      float sc = 0.f;
      for (int x = q * 32; x < q * 32 + 32; ++x) sc += u.r.sfl[x] * P.vis_pal[a * 128 + x];
      u.r.s_pv[q][a] = sc;
    } else {
      const int tt = t - 128, a = tt & 31, q = tt >> 5;
      float sc = 0.f;
      for (int x = q * 32; x < q * 32 + 32; ++x) sc += u.r.sfl[x] * P.aud_pal[a * 128 + x];
      u.r.s_pa[q][a] = sc;
    }
    __syncthreads();

    // ---- F: publish next z + read combine | vis softmax | aud softmax ----
    if (rr < 3 && t < 128) {
      if (t < 64) u.r.zr[t] = zn;
      else        u.r.zi[t - 64] = zn;
    }
    if (t < 64) {
      const int kk = t >> 3, xx = t & 7;
      const float rv = u.r.s_rr[0][kk][xx] + u.r.s_rr[1][kk][xx] + u.r.s_rr[2][kk][xx] + u.r.s_rr[3][kk][xx];
      const float iv = u.r.s_ri[0][kk][xx] + u.r.s_ri[1][kk][xx] + u.r.s_ri[2][kk][xx] + u.r.s_ri[3][kk][xx];
      orow[256 + t] = rv;
      orow[320 + t] = iv;
    } else if (t >= 128 && t < 160) {
      const int a = t - 128;
      float sc = u.r.s_pv[0][a] + u.r.s_pv[1][a] + u.r.s_pv[2][a] + u.r.s_pv[3][a];
      float mx = sc;
      #pragma unroll
      for (int m = 16; m >= 1; m >>= 1) mx = fmaxf(mx, __shfl_xor(mx, m));
      float e = __expf(sc - mx);
      float sm = e;
      #pragma unroll
      for (int m = 16; m >= 1; m >>= 1) sm += __shfl_xor(sm, m);
      u.r.s_pvp[a] = e / sm;
    } else if (t >= 192 && t < 224) {
      const int a = t - 192;
      float sc = u.r.s_pa[0][a] + u.r.s_pa[1][a] + u.r.s_pa[2][a] + u.r.s_pa[3][a];
      float mx = sc;
      #pragma unroll
      for (int m = 16; m >= 1; m >>= 1) mx = fmaxf(mx, __shfl_xor(mx, m));
      float e = __expf(sc - mx);
      float sm = e;
      #pragma unroll
      for (int m = 16; m >= 1; m >>= 1) sm += __shfl_xor(sm, m);
      u.r.s_pap[a] = e / sm;
    }
    __syncthreads();

    // ---- G: palette attend-out + g writes ----
    if (t < 128) {
      float v = 0.f;
      for (int a = 0; a < 32; ++a) v += u.r.s_pvp[a] * P.vis_pal[a * 128 + t];
      u.r.s_vo[t] = v;
    } else {
      const int j = t - 128;
      float v = 0.f;
      for (int a = 0; a < 32; ++a) v += u.r.s_pap[a] * P.aud_pal[a * 128 + j];
      u.r.s_ao[j] = v;
    }
    if (t < 64)       orow[128 + t] = u.r.s_vr[t] * u.r.s_gate;
    else if (t < 128) orow[192 + (t - 64)] = u.r.s_vi[t - 64] * u.r.s_gate;
    __syncthreads();

    // ---- H: exp_r / exp_i ----
    if (t < 64)       orow[384 + t] = u.r.s_vo[t] - u.r.s_ao[64 + t];
    else if (t < 128) orow[448 + (t - 64)] = u.r.s_vo[t] + u.r.s_ao[t - 64];
    __syncthreads();   // loop-end: LDS lifetime + z ready for next B

    // rotate prefetched mem regs
    if (rr < 3) {
      #pragma unroll
      for (int x = 0; x < 8; ++x) { mrC[x] = mrN[x]; miC[x] = miN[x]; }
    }
  }
}

__global__ __launch_bounds__(256) void finalize_k(const int* hist, const float* rowent,
                                                  float* out) {
  const int t = threadIdx.x;
  __shared__ float red[256];
  float se = 0.f;
  for (int i = t; i < 8192; i += 256) se += rowent[i];
  red[t] = se;
  __syncthreads();
  for (int off = 128; off >= 1; off >>= 1) {
    if (t < off) red[t] += red[t + off];
    __syncthreads();
  }
  if (t == 0) out[OFF_SENT] = red[0] / 8192.0f;
  __syncthreads();
  float ne = 0.f;
  if (t < 128) {
    const float pp = (float)hist[t] / 8192.0f;
    ne = -(pp * logf(pp + 1e-10f));
  }
  red[t] = ne;
  __syncthreads();
  for (int off = 128; off >= 1; off >>= 1) {
    if (t < off) red[t] += red[t + off];
    __syncthreads();
  }
  if (t == 0) out[OFF_NENT] = red[0] / logf(128.0f);
}

extern "C" void kernel_launch(void* const* d_in, const int* in_sizes, int n_in,
                              void* d_out, int out_size, void* d_ws, size_t ws_size,
                              hipStream_t stream) {
  (void)in_sizes; (void)n_in; (void)out_size; (void)ws_size;
  Params P;
  P.curr_r   = (const float*)d_in[0];
  P.curr_i   = (const float*)d_in[1];
  P.mem_r    = (const float*)d_in[2];
  P.mem_i    = (const float*)d_in[3];
  P.codebook = (const float*)d_in[4];
  P.qkv_Wr   = (const float*)d_in[5];
  P.qkv_Wi   = (const float*)d_in[6];
  P.qkv_br   = (const float*)d_in[7];
  P.qkv_bi   = (const float*)d_in[8];
  P.quad_Wr  = (const float*)d_in[9];
  P.quad_Wi  = (const float*)d_in[10];
  P.quad_br  = (const float*)d_in[11];
  P.quad_bi  = (const float*)d_in[12];
  P.sens_Wr  = (const float*)d_in[13];
  P.sens_Wi  = (const float*)d_in[14];
  P.sens_br  = (const float*)d_in[15];
  P.sens_bi  = (const float*)d_in[16];
  P.vis_pal  = (const float*)d_in[17];
  P.aud_pal  = (const float*)d_in[18];
  P.gate_W   = (const float*)d_in[19];
  P.gate_b   = (const float*)d_in[20];
  P.addr_W   = (const float*)d_in[21];
  P.addr_b   = (const float*)d_in[22];
  P.ln_gr    = (const float*)d_in[23];
  P.ln_br    = (const float*)d_in[24];
  P.ln_gi    = (const float*)d_in[25];
  P.ln_bi    = (const float*)d_in[26];
  P.out = (float*)d_out;
  P.hist = (int*)d_ws;
  P.rowent = (float*)((char*)d_ws + 512);

  hipMemsetAsync(d_ws, 0, 512, stream);
  main_kernel<<<dim3(1024 + 2048), dim3(256), 0, stream>>>(P);
  finalize_k<<<dim3(1), dim3(256), 0, stream>>>(P.hist, P.rowent, (float*)d_out);
}

// Round 23
// 233.859 us; speedup vs baseline: 2.7246x; 2.7246x over previous
//
#include <hip/hip_runtime.h>
#include <hip/hip_bf16.h>

// SACRSN_v84 — FINAL: R19 champion (234.9us, best of 22 rounds).
// Merged single kernel: VQ path (1024 blocks, exact f64 argmin) + row path
// (8192 blocks: clinears, gates, addr softmax/top3, mem attention, tanh+LN,
// palettes) + finalize. HW transcendentals in row path.

#define NROWS 8
#define RSTRIDE 4736

static constexpr size_t OFF_VQLOSS = 38797312UL;
static constexpr size_t OFF_IDX    = 38805504UL;
static constexpr size_t OFF_SENT   = 38813696UL;
static constexpr size_t OFF_NENT   = 38813697UL;

struct Params {
  const float* curr_r; const float* curr_i;
  const float* mem_r;  const float* mem_i;
  const float* codebook;
  const float* qkv_Wr; const float* qkv_Wi; const float* qkv_br; const float* qkv_bi;
  const float* quad_Wr; const float* quad_Wi; const float* quad_br; const float* quad_bi;
  const float* sens_Wr; const float* sens_Wi; const float* sens_br; const float* sens_bi;
  const float* vis_pal; const float* aud_pal;
  const float* gate_W; const float* gate_b;
  const float* addr_W; const float* addr_b;
  const float* ln_gr; const float* ln_br; const float* ln_gi; const float* ln_bi;
  float* out;
  int* hist;
  float* rowent;
};

__device__ __forceinline__ float ftanh(float x) {
  const float e = __expf(2.0f * x);
  return 1.0f - 2.0f / (e + 1.0f);
}
__device__ __forceinline__ float fsigm(float x) {
  return 1.0f / (1.0f + __expf(-x));
}

union __align__(16) SharedU {
  struct {          // row path (~11.8 KB)
    float zr[64], zi[64];
    float s_qr[64], s_qi[64], s_kr[64], s_ki[64], s_vr[64], s_vi[64];
    float sfl[128];
    float s_sp[4][4][64];
    float lp[4][32];
    float s_eff[32];
    float s_sim[32], s_attn[32];
    float s_rr[4][8][8], s_ri[4][8][8];
    float s_pv[4][32], s_pa[4][32];
    float s_pvp[32], s_pap[32];
    float s_vo[128], s_ao[128];
    float s_wg, s_gate;
  } r;
  struct {          // vq path (~13.3 KB)
    float s_zr[NROWS][64], s_zi[NROWS][64];
    double s_cbn[128];
    double s_dall4[4][256];
    float s_vqls[NROWS];
    int s_idx[NROWS];
  } v;
};

__global__ __launch_bounds__(256) void main_kernel(Params P) {
  __shared__ SharedU u;
  const int t = threadIdx.x;
  const int lane = t & 63;
  const int wv = t >> 6;

  if (blockIdx.x < 1024) {
    // ================= VQ path =================
    const int bid = blockIdx.x;
    {
      const float* cr = P.curr_r + (size_t)bid * (NROWS * 64);
      const float* ci = P.curr_i + (size_t)bid * (NROWS * 64);
      float* zr = &u.v.s_zr[0][0];
      float* zi = &u.v.s_zi[0][0];
      for (int i = t; i < NROWS * 64; i += 256) { zr[i] = cr[i]; zi[i] = ci[i]; }
    }
    {
      const float* cb = P.codebook + (t & 127) * 128 + (t >> 7) * 64;
      double a = 0.0;
      for (int d = 0; d < 64; ++d) { double w = (double)cb[d]; a = fma(w, w, a); }
      __syncthreads();
      ((double*)&u.v.s_dall4[0][0])[t] = a;
      __syncthreads();
      if (t < 128) u.v.s_cbn[t] = ((double*)&u.v.s_dall4[0][0])[t]
                                 + ((double*)&u.v.s_dall4[0][0])[t + 128];
      __syncthreads();
    }
    {
      const int c = t & 127, h = t >> 7;
      const float* cb = P.codebook + c * 128 + h * 64;
      const float (*zb)[64] = h ? u.v.s_zi : u.v.s_zr;
      #pragma unroll 1
      for (int p = 0; p < 2; ++p) {
        double acc[4];
        #pragma unroll
        for (int rr = 0; rr < 4; ++rr) acc[rr] = 0.0;
        for (int d = 0; d < 64; ++d) {
          const double w = (double)cb[d];
          #pragma unroll
          for (int rr = 0; rr < 4; ++rr) acc[rr] = fma(w, (double)zb[p * 4 + rr][d], acc[rr]);
        }
        #pragma unroll
        for (int rr = 0; rr < 4; ++rr) u.v.s_dall4[rr][h * 128 + c] = acc[rr];
        __syncthreads();
        {
          const int r = p * 4 + wv;
          const double d0 = u.v.s_cbn[lane]      - 2.0 * (u.v.s_dall4[wv][lane]      + u.v.s_dall4[wv][128 + lane]);
          const double d1 = u.v.s_cbn[lane + 64] - 2.0 * (u.v.s_dall4[wv][64 + lane] + u.v.s_dall4[wv][192 + lane]);
          double sv = d0; int si = lane;
          if (d1 < sv) { sv = d1; si = lane + 64; }
          #pragma unroll
          for (int m = 1; m <= 32; m <<= 1) {
            double ov = __shfl_xor(sv, m);
            int oi = __shfl_xor(si, m);
            if (ov < sv || (ov == sv && oi < si)) { sv = ov; si = oi; }
          }
          if (lane == 0) { u.v.s_idx[r] = si; atomicAdd(&P.hist[si], 1); }
        }
        __syncthreads();
      }
    }
    {
      #pragma unroll
      for (int rr = 0; rr < 2; ++rr) {
        const int r = wv * 2 + rr;
        const float* cb = P.codebook + (size_t)u.v.s_idx[r] * 128;
        float d0_ = cb[lane] - u.v.s_zr[r][lane];
        float d1_ = cb[64 + lane] - u.v.s_zi[r][lane];
        float v = d0_ * d0_ + d1_ * d1_;
        #pragma unroll
        for (int m = 1; m <= 32; m <<= 1) v += __shfl_xor(v, m);
        if (lane == 0) u.v.s_vqls[r] = 0.25f * v * (1.0f / 128.0f);
      }
    }
    __syncthreads();
    {
      const int j = t & 63, g = t >> 6;
      #pragma unroll
      for (int rr = 0; rr < 4; ++rr) {
        const int r = (g >> 1) * 4 + rr;
        float* orow = P.out + ((size_t)bid * NROWS + r) * RSTRIDE;
        const float* cb = P.codebook + (size_t)u.v.s_idx[r] * 128;
        if ((g & 1) == 0) {
          float z = u.v.s_zr[r][j];
          orow[j] = z + (cb[j] - z);
        } else {
          float z = u.v.s_zi[r][j];
          orow[64 + j] = z + (cb[64 + j] - z);
        }
      }
    }
    if (t < NROWS) {
      P.out[OFF_VQLOSS + (size_t)bid * NROWS + t] = u.v.s_vqls[t];
      P.out[OFF_IDX + (size_t)bid * NROWS + t] = (float)u.v.s_idx[t];
    }
    return;
  }

  // ================= Row path =================
  const int b = blockIdx.x - 1024;
  const size_t bb = (size_t)b;
  const int s = t >> 3, k = t & 7, d0 = k * 8;
  const float* mrp = P.mem_r + ((bb * 32 + s) * 64 + d0);
  const float* mip = P.mem_i + ((bb * 32 + s) * 64 + d0);
  float4 a0 = *(const float4*)mrp, a1 = *(const float4*)(mrp + 4);
  float4 b0 = *(const float4*)mip, b1 = *(const float4*)(mip + 4);
  float mr[8] = {a0.x, a0.y, a0.z, a0.w, a1.x, a1.y, a1.z, a1.w};
  float mi[8] = {b0.x, b0.y, b0.z, b0.w, b1.x, b1.y, b1.z, b1.w};

  if (t < 64)       u.r.zr[t]      = P.curr_r[bb * 64 + t];
  else if (t < 128) u.r.zi[t - 64] = P.curr_i[bb * 64 + (t - 64)];
  __syncthreads();

  float* orow = P.out + bb * RSTRIDE;

  // ---- B: clinears q,k,v,quad (wave=cl) + sens partials ----
  {
    const int j = lane, cl = wv;
    const float *Wr, *Wi, *br_, *bi_;
    if      (cl == 0) { Wr = P.qkv_Wr;        Wi = P.qkv_Wi;        br_ = P.qkv_br;       bi_ = P.qkv_bi;       }
    else if (cl == 1) { Wr = P.qkv_Wr + 4096; Wi = P.qkv_Wi + 4096; br_ = P.qkv_br + 64;  bi_ = P.qkv_bi + 64;  }
    else if (cl == 2) { Wr = P.qkv_Wr + 8192; Wi = P.qkv_Wi + 8192; br_ = P.qkv_br + 128; bi_ = P.qkv_bi + 128; }
    else              { Wr = P.quad_Wr;       Wi = P.quad_Wi;       br_ = P.quad_br;      bi_ = P.quad_bi;      }
    float aRR = 0.f, aRI = 0.f, aIR = 0.f, aII = 0.f;
    for (int d = 0; d < 64; ++d) {
      const float xr = u.r.zr[d], xi = u.r.zi[d];
      const float wr = Wr[d * 64 + j], wi = Wi[d * 64 + j];
      aRR += xr * wr; aRI += xr * wi; aIR += xi * wr; aII += xi * wi;
    }
    const float oR = (aRR + br_[j]) - (aII + bi_[j]);
    const float oI = (aRI + bi_[j]) + (aIR + br_[j]);
    if      (cl == 0) { u.r.s_qr[j] = oR; u.r.s_qi[j] = oI; }
    else if (cl == 1) { u.r.s_kr[j] = oR; u.r.s_ki[j] = oI; }
    else if (cl == 2) { u.r.s_vr[j] = oR; u.r.s_vi[j] = oI; }
    else              { orow[512 + j] = -oI; orow[576 + j] = oR; }
    float bRR = 0.f, bRI = 0.f, bIR = 0.f, bII = 0.f;
    for (int dd = 0; dd < 16; ++dd) {
      const int d = wv * 16 + dd;
      const float xr = u.r.zr[d], xi = u.r.zi[d];
      const float wr = P.sens_Wr[d * 64 + j], wi = P.sens_Wi[d * 64 + j];
      bRR += xr * wr; bRI += xr * wi; bIR += xi * wr; bII += xi * wi;
    }
    u.r.s_sp[wv][0][j] = bRR; u.r.s_sp[wv][1][j] = bRI;
    u.r.s_sp[wv][2][j] = bIR; u.r.s_sp[wv][3][j] = bII;
  }
  __syncthreads();

  // ---- C: sim partials + addr partials + wgate + gate ----
  {
    float sp = 0.f;
    #pragma unroll
    for (int x = 0; x < 8; ++x) sp += mr[x] * u.r.zr[d0 + x] + mi[x] * u.r.zi[d0 + x];
    sp += __shfl_xor(sp, 1); sp += __shfl_xor(sp, 2); sp += __shfl_xor(sp, 4);
    if (k == 0) u.r.s_sim[s] = sp;
  }
  if (t < 128) {
    const int q = t >> 5, l = t & 31;
    const float* zz = (q < 2) ? u.r.zr : u.r.zi;
    const int zb = (q & 1) * 32;
    float a = 0.f;
    for (int i = 0; i < 32; ++i) a += zz[zb + i] * P.addr_W[(q * 32 + i) * 32 + l];
    u.r.lp[q][l] = a;
  } else if (t < 192) {
    const int j = t - 128;
    float tw = u.r.zr[j] * P.gate_W[j] + u.r.zi[j] * P.gate_W[64 + j];
    #pragma unroll
    for (int m = 1; m <= 32; m <<= 1) tw += __shfl_xor(tw, m);
    if (j == 0) u.r.s_wg = tw;
  } else {
    const int j = t - 192;
    float g = u.r.s_qr[j] * u.r.s_kr[j] + u.r.s_qi[j] * u.r.s_ki[j];
    #pragma unroll
    for (int m = 1; m <= 32; m <<= 1) g += __shfl_xor(g, m);
    if (j == 0) u.r.s_gate = fsigm(g);
  }
  __syncthreads();

  // ---- D: sim softmax | addr softmax/top3/eff | sens combine ----
  if (t < 32) {
    float v = u.r.s_sim[t];
    float mx = v;
    #pragma unroll
    for (int m = 16; m >= 1; m >>= 1) mx = fmaxf(mx, __shfl_xor(mx, m));
    float e = __expf(v - mx);
    float sm = e;
    #pragma unroll
    for (int m = 16; m >= 1; m >>= 1) sm += __shfl_xor(sm, m);
    u.r.s_attn[t] = e / sm;
  } else if (t >= 64 && t < 96) {
    const int l = t - 64;
    float lg = u.r.lp[0][l] + u.r.lp[1][l] + u.r.lp[2][l] + u.r.lp[3][l] + P.addr_b[l];
    float mx = lg;
    #pragma unroll
    for (int m = 16; m >= 1; m >>= 1) mx = fmaxf(mx, __shfl_xor(mx, m));
    float e = __expf(lg - mx);
    float sm = e;
    #pragma unroll
    for (int m = 16; m >= 1; m >>= 1) sm += __shfl_xor(sm, m);
    const float w = e / sm;
    float es = -(w * __logf(w + 1e-10f));
    #pragma unroll
    for (int m = 16; m >= 1; m >>= 1) es += __shfl_xor(es, m);
    if (l == 0) P.rowent[b] = es;
    const float myw = w;
    bool picked = false;
    float val = w; int idx = l;
    float sumtop = 0.f;
    #pragma unroll
    for (int it = 0; it < 3; ++it) {
      float v2 = val; int i2 = idx;
      #pragma unroll
      for (int m = 16; m >= 1; m >>= 1) {
        float ov = __shfl_xor(v2, m); int oi = __shfl_xor(i2, m);
        if (ov > v2 || (ov == v2 && oi < i2)) { v2 = ov; i2 = oi; }
      }
      sumtop += v2;
      if (l == i2) { picked = true; val = -1e30f; }
    }
    const float wgate = fsigm(u.r.s_wg + P.gate_b[0]);
    u.r.s_eff[l] = picked ? wgate * (myw / (sumtop + 1e-6f)) : 0.f;
  } else if (t >= 128 && t < 192) {
    const int j = t - 128;
    const float aRR = u.r.s_sp[0][0][j] + u.r.s_sp[1][0][j] + u.r.s_sp[2][0][j] + u.r.s_sp[3][0][j];
    const float aRI = u.r.s_sp[0][1][j] + u.r.s_sp[1][1][j] + u.r.s_sp[2][1][j] + u.r.s_sp[3][1][j];
    const float aIR = u.r.s_sp[0][2][j] + u.r.s_sp[1][2][j] + u.r.s_sp[2][2][j] + u.r.s_sp[3][2][j];
    const float aII = u.r.s_sp[0][3][j] + u.r.s_sp[1][3][j] + u.r.s_sp[2][3][j] + u.r.s_sp[3][3][j];
    const float oR = (aRR + P.sens_br[j]) - (aII + P.sens_bi[j]);
    const float oI = (aRI + P.sens_bi[j]) + (aIR + P.sens_br[j]);
    u.r.sfl[j] = oR; u.r.sfl[64 + j] = oI;
  }
  __syncthreads();

  // ---- E: read partials + tanh/LN + palette partials ----
  const float aw = u.r.s_attn[s];
  {
    float pr[8], pi[8];
    #pragma unroll
    for (int x = 0; x < 8; ++x) { pr[x] = aw * mr[x]; pi[x] = aw * mi[x]; }
    #pragma unroll
    for (int m = 8; m <= 32; m <<= 1) {
      #pragma unroll
      for (int x = 0; x < 8; ++x) { pr[x] += __shfl_xor(pr[x], m); pi[x] += __shfl_xor(pi[x], m); }
    }
    if (lane < 8) {
      #pragma unroll
      for (int x = 0; x < 8; ++x) { u.r.s_rr[wv][lane][x] = pr[x]; u.r.s_ri[wv][lane][x] = pi[x]; }
    }
  }
  {
    const float eff = u.r.s_eff[s];
    float nr[8], ni[8];
    #pragma unroll
    for (int x = 0; x < 8; ++x) {
      nr[x] = ftanh(mr[x] + eff * (u.r.zr[d0 + x] - mr[x]));
      ni[x] = ftanh(mi[x] + eff * (u.r.zi[d0 + x] - mi[x]));
    }
    float sR = 0.f, sI = 0.f;
    #pragma unroll
    for (int x = 0; x < 8; ++x) { sR += nr[x]; sI += ni[x]; }
    sR += __shfl_xor(sR, 1); sR += __shfl_xor(sR, 2); sR += __shfl_xor(sR, 4);
    sI += __shfl_xor(sI, 1); sI += __shfl_xor(sI, 2); sI += __shfl_xor(sI, 4);
    const float mR = sR * (1.f / 64.f), mI = sI * (1.f / 64.f);
    float vR = 0.f, vI = 0.f;
    #pragma unroll
    for (int x = 0; x < 8; ++x) {
      const float dr = nr[x] - mR; vR += dr * dr;
      const float di = ni[x] - mI; vI += di * di;
    }
    vR += __shfl_xor(vR, 1); vR += __shfl_xor(vR, 2); vR += __shfl_xor(vR, 4);
    vI += __shfl_xor(vI, 1); vI += __shfl_xor(vI, 2); vI += __shfl_xor(vI, 4);
    const float invR = 1.f / sqrtf(vR * (1.f / 64.f) + 1e-6f);
    const float invI = 1.f / sqrtf(vI * (1.f / 64.f) + 1e-6f);
    float oR[8], oI[8];
    #pragma unroll
    for (int x = 0; x < 8; ++x) {
      const int d = d0 + x;
      oR[x] = (nr[x] - mR) * invR * P.ln_gr[d] + P.ln_br[d];
      oI[x] = (ni[x] - mI) * invI * P.ln_gi[d] + P.ln_bi[d];
    }
    *(float4*)&orow[640 + s * 64 + d0]      = make_float4(oR[0], oR[1], oR[2], oR[3]);
    *(float4*)&orow[640 + s * 64 + d0 + 4]  = make_float4(oR[4], oR[5], oR[6], oR[7]);
    *(float4*)&orow[2688 + s * 64 + d0]     = make_float4(oI[0], oI[1], oI[2], oI[3]);
    *(float4*)&orow[2688 + s * 64 + d0 + 4] = make_float4(oI[4], oI[5], oI[6], oI[7]);
  }
  if (t < 128) {
    const int a = t & 31, q = t >> 5;
    float sc = 0.f;
    for (int x = q * 32; x < q * 32 + 32; ++x) sc += u.r.sfl[x] * P.vis_pal[a * 128 + x];
    u.r.s_pv[q][a] = sc;
  } else {
    const int tt = t - 128, a = tt & 31, q = tt >> 5;
    float sc = 0.f;
    for (int x = q * 32; x < q * 32 + 32; ++x) sc += u.r.sfl[x] * P.aud_pal[a * 128 + x];
    u.r.s_pa[q][a] = sc;
  }
  __syncthreads();

  // ---- F: read combine | vis softmax | aud softmax ----
  if (t < 64) {
    const int kk = t >> 3, xx = t & 7;
    const float rv = u.r.s_rr[0][kk][xx] + u.r.s_rr[1][kk][xx] + u.r.s_rr[2][kk][xx] + u.r.s_rr[3][kk][xx];
    const float iv = u.r.s_ri[0][kk][xx] + u.r.s_ri[1][kk][xx] + u.r.s_ri[2][kk][xx] + u.r.s_ri[3][kk][xx];
    orow[256 + t] = rv;
    orow[320 + t] = iv;
  } else if (t >= 128 && t < 160) {
    const int a = t - 128;
    float sc = u.r.s_pv[0][a] + u.r.s_pv[1][a] + u.r.s_pv[2][a] + u.r.s_pv[3][a];
    float mx = sc;
    #pragma unroll
    for (int m = 16; m >= 1; m >>= 1) mx = fmaxf(mx, __shfl_xor(mx, m));
    float e = __expf(sc - mx);
    float sm = e;
    #pragma unroll
    for (int m = 16; m >= 1; m >>= 1) sm += __shfl_xor(sm, m);
    u.r.s_pvp[a] = e / sm;
  } else if (t >= 192 && t < 224) {
    const int a = t - 192;
    float sc = u.r.s_pa[0][a] + u.r.s_pa[1][a] + u.r.s_pa[2][a] + u.r.s_pa[3][a];
    float mx = sc;
    #pragma unroll
    for (int m = 16; m >= 1; m >>= 1) mx = fmaxf(mx, __shfl_xor(mx, m));
    float e = __expf(sc - mx);
    float sm = e;
    #pragma unroll
    for (int m = 16; m >= 1; m >>= 1) sm += __shfl_xor(sm, m);
    u.r.s_pap[a] = e / sm;
  }
  __syncthreads();

  // ---- G: palette attend-out + g writes ----
  if (t < 128) {
    float v = 0.f;
    for (int a = 0; a < 32; ++a) v += u.r.s_pvp[a] * P.vis_pal[a * 128 + t];
    u.r.s_vo[t] = v;
  } else {
    const int j = t - 128;
    float v = 0.f;
    for (int a = 0; a < 32; ++a) v += u.r.s_pap[a] * P.aud_pal[a * 128 + j];
    u.r.s_ao[j] = v;
  }
  if (t < 64)       orow[128 + t] = u.r.s_vr[t] * u.r.s_gate;
  else if (t < 128) orow[192 + (t - 64)] = u.r.s_vi[t - 64] * u.r.s_gate;
  __syncthreads();

  // ---- H: exp_r / exp_i ----
  if (t < 64)       orow[384 + t] = u.r.s_vo[t] - u.r.s_ao[64 + t];
  else if (t < 128) orow[448 + (t - 64)] = u.r.s_vo[t] + u.r.s_ao[t - 64];
}

__global__ __launch_bounds__(256) void finalize_k(const int* hist, const float* rowent,
                                                  float* out) {
  const int t = threadIdx.x;
  __shared__ float red[256];
  float se = 0.f;
  for (int i = t; i < 8192; i += 256) se += rowent[i];
  red[t] = se;
  __syncthreads();
  for (int off = 128; off >= 1; off >>= 1) {
    if (t < off) red[t] += red[t + off];
    __syncthreads();
  }
  if (t == 0) out[OFF_SENT] = red[0] / 8192.0f;
  __syncthreads();
  float ne = 0.f;
  if (t < 128) {
    const float pp = (float)hist[t] / 8192.0f;
    ne = -(pp * logf(pp + 1e-10f));
  }
  red[t] = ne;
  __syncthreads();
  for (int off = 128; off >= 1; off >>= 1) {
    if (t < off) red[t] += red[t + off];
    __syncthreads();
  }
  if (t == 0) out[OFF_NENT] = red[0] / logf(128.0f);
}

extern "C" void kernel_launch(void* const* d_in, const int* in_sizes, int n_in,
                              void* d_out, int out_size, void* d_ws, size_t ws_size,
                              hipStream_t stream) {
  (void)in_sizes; (void)n_in; (void)out_size; (void)ws_size;
  Params P;
  P.curr_r   = (const float*)d_in[0];
  P.curr_i   = (const float*)d_in[1];
  P.mem_r    = (const float*)d_in[2];
  P.mem_i    = (const float*)d_in[3];
  P.codebook = (const float*)d_in[4];
  P.qkv_Wr   = (const float*)d_in[5];
  P.qkv_Wi   = (const float*)d_in[6];
  P.qkv_br   = (const float*)d_in[7];
  P.qkv_bi   = (const float*)d_in[8];
  P.quad_Wr  = (const float*)d_in[9];
  P.quad_Wi  = (const float*)d_in[10];
  P.quad_br  = (const float*)d_in[11];
  P.quad_bi  = (const float*)d_in[12];
  P.sens_Wr  = (const float*)d_in[13];
  P.sens_Wi  = (const float*)d_in[14];
  P.sens_br  = (const float*)d_in[15];
  P.sens_bi  = (const float*)d_in[16];
  P.vis_pal  = (const float*)d_in[17];
  P.aud_pal  = (const float*)d_in[18];
  P.gate_W   = (const float*)d_in[19];
  P.gate_b   = (const float*)d_in[20];
  P.addr_W   = (const float*)d_in[21];
  P.addr_b   = (const float*)d_in[22];
  P.ln_gr    = (const float*)d_in[23];
  P.ln_br    = (const float*)d_in[24];
  P.ln_gi    = (const float*)d_in[25];
  P.ln_bi    = (const float*)d_in[26];
  P.out = (float*)d_out;
  P.hist = (int*)d_ws;
  P.rowent = (float*)((char*)d_ws + 512);

  hipMemsetAsync(d_ws, 0, 512, stream);
  main_kernel<<<dim3(1024 + 8192), dim3(256), 0, stream>>>(P);
  finalize_k<<<dim3(1), dim3(256), 0, stream>>>(P.hist, P.rowent, (float*)d_out);
}